// Round 10
// baseline (43.467 us; speedup 1.0000x reference)
//
#include <hip/hip_runtime.h>
#include <hip/hip_bf16.h>

#define N_TOT 4096
#define BATCH 2048
#define DIM   256
#define NCLS  100
#define NSLC  4            // csum slices
#define NTILE 32           // 4096 / 128
#define NPAIR 528          // NTILE*(NTILE+1)/2
#define NWORK (NPAIR + NCLS * NSLC)   // 928 blocks

typedef __attribute__((ext_vector_type(8))) short short8;
typedef __attribute__((ext_vector_type(4))) float floatx4;
typedef __attribute__((ext_vector_type(4))) unsigned short ushortx4;

typedef __attribute__((address_space(1))) const unsigned int as1c_uint;
typedef __attribute__((address_space(3))) unsigned int as3_uint;

// async global->LDS, 16B per lane; lds dest is wave-uniform base (+lane*16 by HW)
__device__ __forceinline__ void gload_lds16(const void* g, void* lds_base) {
    __builtin_amdgcn_global_load_lds((as1c_uint*)g, (as3_uint*)lds_base, 16, 0, 0);
}

__device__ __forceinline__ unsigned short f2bf(float x) {
    __hip_bfloat16 h = __float2bfloat16(x);
    return *(unsigned short*)&h;
}

// ---------------------------------------------------------------------------
// K1: normalize rows of concat(z_i, z_j). Wave-per-row; bf16+fp32 copies;
//     labels via ballot; zero final counter.
// ---------------------------------------------------------------------------
__global__ __launch_bounds__(256) void prep_kernel(const float* __restrict__ z_i,
                                                   const float* __restrict__ z_j,
                                                   const float* __restrict__ dist,
                                                   unsigned short* __restrict__ zb,
                                                   float* __restrict__ zf,
                                                   int* __restrict__ lab,
                                                   int* __restrict__ counter)
{
    const int t = threadIdx.x;
    const int lane = t & 63, wv = t >> 6;
    if (blockIdx.x == 0 && t == 0) *counter = 0;

    #pragma unroll
    for (int it = 0; it < 2; ++it) {
        const int n = blockIdx.x * 8 + it * 4 + wv;
        const float* src = (n < BATCH) ? (z_i + (size_t)n * DIM)
                                       : (z_j + (size_t)(n - BATCH) * DIM);
        const floatx4 v = *(const floatx4*)(src + lane * 4);
        float ss = v[0]*v[0] + v[1]*v[1] + v[2]*v[2] + v[3]*v[3];
        #pragma unroll
        for (int s = 32; s; s >>= 1) ss += __shfl_xor(ss, s);
        const float rn = 1.0f / sqrtf(ss);

        floatx4 zn;
        zn[0] = v[0]*rn; zn[1] = v[1]*rn; zn[2] = v[2]*rn; zn[3] = v[3]*rn;
        *(floatx4*)(zf + (size_t)n * DIM + lane * 4) = zn;
        ushortx4 zp;
        zp[0] = f2bf(zn[0]); zp[1] = f2bf(zn[1]);
        zp[2] = f2bf(zn[2]); zp[3] = f2bf(zn[3]);
        *(ushortx4*)(zb + (size_t)n * DIM + lane * 4) = zp;

        if (n < BATCH) {
            float d0 = 0.f, d1 = 0.f;
            if (lane < 50) {
                d0 = dist[(size_t)n * NCLS + 2 * lane];
                d1 = dist[(size_t)n * NCLS + 2 * lane + 1];
            }
            const unsigned long long m0 = __ballot(d0 > 0.5f);
            const unsigned long long m1 = __ballot(d1 > 0.5f);
            if (lane == 0) {
                const int l = m0 ? 2 * __builtin_ctzll(m0)
                                 : 2 * __builtin_ctzll(m1) + 1;
                lab[n] = l;
                lab[n + BATCH] = l;
            }
        }
    }
}

// ---------------------------------------------------------------------------
// K2 (fused): blocks [0,NPAIR) = den MFMA tiles; [NPAIR,NWORK) = class sums.
//     den: 128x128 tile, FULL K=256 staged once into LDS (A 64KB + B 64KB),
//     ONE barrier, then 8 barrier-free K-steps of ds_read+MFMA.
//     Swizzle (row stride 512B = 16-way conflict otherwise): 16B slot s of
//     row r holds global chunk g = s ^ (r&31); read: slot = chunk ^ (r&31).
// ---------------------------------------------------------------------------
__global__ __launch_bounds__(256, 1) void work_kernel(const __hip_bfloat16* __restrict__ zbp,
                                                      const float* __restrict__ zf,
                                                      const int* __restrict__ lab,
                                                      float* __restrict__ den_part,
                                                      float* __restrict__ csum_part)
{
    __shared__ short tA[128 * 256];      // 64 KB
    __shared__ short tB[128 * 256];      // 64 KB
    __shared__ float red_rs[2][128];
    __shared__ float red_cs[2][128];
    __shared__ float cred[4][DIM];       // csum reduction

    const int t = threadIdx.x;
    const int lane = t & 63, wv = t >> 6;

    if (blockIdx.x >= NPAIR) {
        // ---------------- csum path ----------------
        const int b = blockIdx.x - NPAIR;          // 0..399
        const int c = b % NCLS;
        const int s = b / NCLS;
        const int m0 = s * 1024 + wv * 256;

        floatx4 acc = {0.f, 0.f, 0.f, 0.f};
        #pragma unroll
        for (int g = 0; g < 4; ++g) {
            const int m = m0 + g * 64 + lane;
            unsigned long long mask = __ballot(lab[m] == c);
            while (mask) {
                const int bit = __builtin_ctzll(mask);
                mask &= mask - 1;
                const int mm = m0 + g * 64 + bit;
                acc += *(const floatx4*)(zf + (size_t)mm * DIM + lane * 4);
            }
        }
        *(floatx4*)&cred[wv][lane * 4] = acc;
        __syncthreads();
        if (t < DIM)
            csum_part[((size_t)s * NCLS + c) * DIM + t] =
                cred[0][t] + cred[1][t] + cred[2][t] + cred[3][t];
        return;
    }

    // ---------------- den path ----------------
    int p = blockIdx.x;
    int bi = 0;
    while (p >= NTILE - bi) { p -= NTILE - bi; ++bi; }
    const int bj = bi + p;

    const int wy = wv >> 1, wx = wv & 1;
    const int lr = lane & 15;
    const int lg = lane >> 4;            // 0..3

    const short* z = (const short*)zbp;
    const int row0 = bi * 128;
    const int col0 = bj * 128;

    // ---- single staging burst: full K=256 for both panels
    // each issue: 64 lanes = 2 rows x 32 slots of 16B; lane's global chunk
    // g = slot ^ (r&31)  (inverse of the read swizzle)
    {
        const int rsub = lane >> 5;              // 0..1 row within pair
        const int slot = lane & 31;              // LDS 16B slot in row
        #pragma unroll
        for (int q = 0; q < 16; ++q) {
            const int base_row = wv * 32 + q * 2;
            const int r = base_row + rsub;
            const int g = slot ^ (r & 31);
            gload_lds16(z + (size_t)(row0 + r) * DIM + g * 8,
                        (char*)tA + base_row * 512);
            gload_lds16(z + (size_t)(col0 + r) * DIM + g * 8,
                        (char*)tB + base_row * 512);
        }
    }
    __syncthreads();    // single drain: all 32 issues/thread complete

    floatx4 acc[4][4] = {};
    #pragma unroll
    for (int ks = 0; ks < 8; ++ks) {
        short8 a[4], bb[4];
        #pragma unroll
        for (int i = 0; i < 4; ++i) {
            const int row = wy * 64 + i * 16 + lr;
            const int sl  = (ks * 4 + lg) ^ (row & 31);
            a[i] = *(const short8*)((const char*)tA + row * 512 + sl * 16);
        }
        #pragma unroll
        for (int j = 0; j < 4; ++j) {
            const int col = wx * 64 + j * 16 + lr;
            const int sl  = (ks * 4 + lg) ^ (col & 31);
            bb[j] = *(const short8*)((const char*)tB + col * 512 + sl * 16);
        }
        #pragma unroll
        for (int i = 0; i < 4; ++i)
            #pragma unroll
            for (int j = 0; j < 4; ++j)
                acc[i][j] = __builtin_amdgcn_mfma_f32_16x16x32_bf16(a[i], bb[j], acc[i][j], 0, 0, 0);
    }

    // ---- epilogue: e = off-diag exp(sim); row sums + col sums
    float rs[4][4] = {};
    float cs[4]    = {};
    #pragma unroll
    for (int i = 0; i < 4; ++i) {
        #pragma unroll
        for (int j = 0; j < 4; ++j) {
            const int gcol = col0 + wx * 64 + j * 16 + lr;
            #pragma unroll
            for (int r = 0; r < 4; ++r) {
                const int grow = row0 + wy * 64 + i * 16 + lg * 4 + r;
                const float e = (grow == gcol) ? 0.0f : __expf(acc[i][j][r]);
                rs[i][r] += e;
                cs[j]    += e;
            }
        }
    }
    #pragma unroll
    for (int i = 0; i < 4; ++i)
        #pragma unroll
        for (int r = 0; r < 4; ++r) {
            float v = rs[i][r];
            v += __shfl_xor(v, 1); v += __shfl_xor(v, 2);
            v += __shfl_xor(v, 4); v += __shfl_xor(v, 8);
            rs[i][r] = v;
        }
    if (lr == 0)
        #pragma unroll
        for (int i = 0; i < 4; ++i)
            #pragma unroll
            for (int r = 0; r < 4; ++r)
                red_rs[wx][wy * 64 + i * 16 + lg * 4 + r] = rs[i][r];

    #pragma unroll
    for (int j = 0; j < 4; ++j) {
        float v = cs[j];
        v += __shfl_xor(v, 16); v += __shfl_xor(v, 32);
        cs[j] = v;
    }
    if (lane < 16)
        #pragma unroll
        for (int j = 0; j < 4; ++j)
            red_cs[wy][wx * 64 + j * 16 + lr] = cs[j];

    __syncthreads();
    if (t < 128) {
        den_part[(size_t)bj * N_TOT + row0 + t] = red_rs[0][t] + red_rs[1][t];
        if (bi != bj)
            den_part[(size_t)bi * N_TOT + col0 + t] = red_cs[0][t] + red_cs[1][t];
    }
}

// ---------------------------------------------------------------------------
// K3: per-row finalize + last-block final reduce (deterministic order).
//     nom = zf[n].csum[lab[n]] - 1; den = sum of 32 partials.
// ---------------------------------------------------------------------------
__global__ __launch_bounds__(256) void final_kernel(const float* __restrict__ zf,
                                                    const int* __restrict__ lab,
                                                    const float* __restrict__ csum_part,
                                                    const float* __restrict__ den_part,
                                                    float* __restrict__ partial,
                                                    int* __restrict__ counter,
                                                    float* __restrict__ out)
{
    const int t = threadIdx.x;
    const int lane = t & 63, wv = t >> 6;

    float bsum = 0.0f;
    #pragma unroll
    for (int it = 0; it < 2; ++it) {
        const int n = blockIdx.x * 8 + it * 4 + wv;
        const int c = lab[n];

        const floatx4 zv = *(const floatx4*)(zf + (size_t)n * DIM + lane * 4);
        floatx4 sv = {0.f, 0.f, 0.f, 0.f};
        #pragma unroll
        for (int s = 0; s < NSLC; ++s)
            sv += *(const floatx4*)(csum_part + ((size_t)s * NCLS + c) * DIM + lane * 4);

        float pd = zv[0]*sv[0] + zv[1]*sv[1] + zv[2]*sv[2] + zv[3]*sv[3];
        float dd = (lane < NTILE) ? den_part[(size_t)lane * N_TOT + n] : 0.0f;
        #pragma unroll
        for (int sh = 32; sh; sh >>= 1) {
            pd += __shfl_xor(pd, sh);
            dd += __shfl_xor(dd, sh);
        }
        bsum += (pd - 1.0f) / dd;
    }

    __shared__ float w[4];
    __shared__ int amlast;
    if (lane == 0) w[wv] = bsum;
    __syncthreads();
    if (t == 0) {
        partial[blockIdx.x] = w[0] + w[1] + w[2] + w[3];
        __threadfence();
        amlast = (atomicAdd(counter, 1) == (int)gridDim.x - 1);
    }
    __syncthreads();
    if (amlast) {
        __threadfence();
        float s = partial[t] + partial[t + 256];
        #pragma unroll
        for (int sh = 32; sh; sh >>= 1) s += __shfl_xor(s, sh);
        if (lane == 0) w[wv] = s;
        __syncthreads();
        if (t == 0)
            out[0] = (w[0] + w[1] + w[2] + w[3]) / (float)N_TOT;
    }
}

// ---------------------------------------------------------------------------
extern "C" void kernel_launch(void* const* d_in, const int* in_sizes, int n_in,
                              void* d_out, int out_size, void* d_ws, size_t ws_size,
                              hipStream_t stream)
{
    const float* z_i  = (const float*)d_in[0];
    const float* z_j  = (const float*)d_in[1];
    // d_in[2] (z_n) unused by the reference
    const float* dist = (const float*)d_in[3];

    char* ws = (char*)d_ws;
    unsigned short* zb = (unsigned short*)ws;                                   // 2 MB
    float* zf        = (float*)(ws + 2u * 1024 * 1024);                         // 4 MB
    int*   lab       = (int*)  (ws + 6u * 1024 * 1024);                         // 16 KB
    float* csum_part = (float*)(ws + 6u * 1024 * 1024 + 16 * 1024);             // 400 KB
    float* den_part  = (float*)(ws + 6u * 1024 * 1024 + 416 * 1024);            // 512 KB
    float* partial   = (float*)(ws + 6u * 1024 * 1024 + 928 * 1024);            // 2 KB
    int*   counter   = (int*)  (ws + 6u * 1024 * 1024 + 930 * 1024);            // 4 B

    float* out = (float*)d_out;

    hipLaunchKernelGGL(prep_kernel, dim3(512), dim3(256), 0, stream,
                       z_i, z_j, dist, zb, zf, lab, counter);
    hipLaunchKernelGGL(work_kernel, dim3(NWORK), dim3(256), 0, stream,
                       (const __hip_bfloat16*)zb, zf, lab, den_part, csum_part);
    hipLaunchKernelGGL(final_kernel, dim3(N_TOT / 8), dim3(256), 0, stream,
                       zf, lab, csum_part, den_part, partial, counter, out);
}